// Round 1
// baseline (173.967 us; speedup 1.0000x reference)
//
#include <hip/hip_runtime.h>
#include <cmath>

#define WIN 11
#define HALO 5
#define IMG 512
#define NIMG 48
#define TS 64                         /* output tile: 64x64 */
#define HR (TS + 2*HALO)              /* 74 h-blurred rows held in LDS */
#define NTILE (IMG/TS)                /* 8 tiles per axis */
#define NBLK (NIMG*NTILE*NTILE)       /* 3072 blocks / partials */
#define NPIX (16.0 * 3.0 * 512.0 * 512.0)

typedef _Float16 f16;
typedef _Float16 h2 __attribute__((ext_vector_type(2)));

struct GaussW { float w[WIN]; };

__device__ __forceinline__ unsigned pk2(float a, float b) {
    auto h = __builtin_amdgcn_cvt_pkrtz(a, b);
    return __builtin_bit_cast(unsigned, h);
}
__device__ __forceinline__ h2 uph(unsigned u) {
    return __builtin_bit_cast(h2, u);
}

__global__ void __launch_bounds__(64) zero_kernel(float* out) {
    if (threadIdx.x == 0) out[0] = 0.f;
}

__global__ void __launch_bounds__(64) finish_kernel(float* out) {
    if (threadIdx.x == 0)
        out[0] = 1.0f - out[0] * (float)(1.0 / NPIX);
}

// ---------------- Fused h-blur + v-blur + SSIM, one 64x64 tile per block ----
// Phase 1: 256 thr = 16 colgroups x 16 rows; 5 passes cover 74 halo'd rows.
//   fp32 horizontal blur of {x, y, x^2+y^2, xy}, packed fp16 col-pairs to LDS.
//   Even col-pairs -> LDS idx 0..15, odd -> 16..31 (16B lane stride on
//   ds_write_b128 instead of 32B: conflict-optimal).
// Phase 2: 256 thr = 32 col-pairs x 8 rowgroups; each thread 8 out rows x 2
//   cols in two chunks of {14 ds_read_b128, 4 outputs} (caps live VGPRs).
//   SSIM summed in order-independent fashion, so the col-pair swizzle is free.
// Eliminates the 96MB ws write + 96MB re-read of the two-pass version.
template<int USE_ATOMIC>
__global__ void __launch_bounds__(256) fused_ssim(
        const float* __restrict__ xin, const float* __restrict__ yin,
        float* __restrict__ outp, GaussW W) {
    __shared__ uint4 hb[HR][32];      /* 74 * 512B = 37,888 B -> 4 blocks/CU */
    __shared__ float wsum[4];
    const int tid = threadIdx.x;
    const int tx = blockIdx.x, ty = blockIdx.y;
    const size_t ibase = (size_t)blockIdx.z * (size_t)(IMG * IMG);
    const float* __restrict__ xb = xin + ibase;
    const float* __restrict__ yb = yin + ibase;

    // ---- phase 1: horizontal blur of image rows ty*64-5 .. ty*64+68 ----
    const int cg  = tid & 15;                 /* 4 output cols per thread */
    const int rr  = tid >> 4;
    const int gx0 = tx * TS + cg * 4 - HALO;  /* 14-col window gx0..gx0+13 */
    const bool cint = (gx0 >= 0) && (gx0 + 13 < IMG);

    #pragma unroll
    for (int it = 0; it < 5; ++it) {
        const int r = it * 16 + rr;           /* hb row 0..79, keep r<74 */
        if (r < HR) {
            const int gy = ty * TS - HALO + r;
            if ((unsigned)gy < IMG) {
                const float* xr = xb + (size_t)gy * IMG;
                const float* yr = yb + (size_t)gy * IMG;
                float xv[14], yv[14];
                if (cint) {
                    xv[0] = xr[gx0];  yv[0] = yr[gx0];
                    #pragma unroll
                    for (int q = 0; q < 3; ++q) {     /* 16B-aligned float4s */
                        float4 a = *(const float4*)(xr + gx0 + 1 + 4*q);
                        float4 b = *(const float4*)(yr + gx0 + 1 + 4*q);
                        xv[1+4*q]=a.x; xv[2+4*q]=a.y; xv[3+4*q]=a.z; xv[4+4*q]=a.w;
                        yv[1+4*q]=b.x; yv[2+4*q]=b.y; yv[3+4*q]=b.z; yv[4+4*q]=b.w;
                    }
                    xv[13] = xr[gx0 + 13];  yv[13] = yr[gx0 + 13];
                } else {
                    #pragma unroll
                    for (int j = 0; j < 14; ++j) {
                        int gx = gx0 + j;
                        bool ok = ((unsigned)gx < IMG);
                        xv[j] = ok ? xr[gx] : 0.f;
                        yv[j] = ok ? yr[gx] : 0.f;
                    }
                }
                float ax[4]  = {0,0,0,0}, ay[4]  = {0,0,0,0};
                float as_[4] = {0,0,0,0}, axy[4] = {0,0,0,0};
                #pragma unroll
                for (int j = 0; j < 14; ++j) {
                    float xs = xv[j], ys = yv[j];
                    float xy = xs * ys;
                    float ss = fmaf(xs, xs, ys * ys);   /* x^2+y^2 one field */
                    #pragma unroll
                    for (int o = 0; o < 4; ++o) {
                        int k = j - o;
                        if (k >= 0 && k < WIN) {
                            float wk = W.w[k];
                            ax[o]  += wk * xs;  ay[o]  += wk * ys;
                            as_[o] += wk * ss;  axy[o] += wk * xy;
                        }
                    }
                }
                uint4 u0, u1;
                u0.x = pk2(ax[0],  ax[1]);  u0.y = pk2(ay[0],  ay[1]);
                u0.z = pk2(as_[0], as_[1]); u0.w = pk2(axy[0], axy[1]);
                u1.x = pk2(ax[2],  ax[3]);  u1.y = pk2(ay[2],  ay[3]);
                u1.z = pk2(as_[2], as_[3]); u1.w = pk2(axy[2], axy[3]);
                hb[r][cg]      = u0;          /* even col-pair */
                hb[r][cg + 16] = u1;          /* odd col-pair  */
            } else {
                uint4 z = make_uint4(0u, 0u, 0u, 0u);
                hb[r][cg]      = z;
                hb[r][cg + 16] = z;
            }
        }
    }
    __syncthreads();

    // ---- phase 2: vertical blur (fp16 packed) + SSIM + block reduce ----
    const int idx = tid & 31;                 /* LDS col-pair slot */
    const int r0  = (tid >> 5) * 8;           /* 8 output rows per thread */

    h2 w2[WIN];
    #pragma unroll
    for (int k = 0; k < WIN; ++k) {
        f16 wk = (f16)W.w[k];
        w2[k] = (h2){wk, wk};
    }

    const float C1 = 0.01f * 0.01f;
    const float C2 = 0.03f * 0.03f;
    float local = 0.f;
    #pragma unroll
    for (int half = 0; half < 2; ++half) {
        const int rbase = r0 + half * 4;
        uint4 v[14];
        #pragma unroll
        for (int j = 0; j < 14; ++j) v[j] = hb[rbase + j][idx];
        #pragma unroll
        for (int o = 0; o < 4; ++o) {
            h2 a0 = (h2){(f16)0,(f16)0}, a1 = a0, a2 = a0, a3 = a0;
            #pragma unroll
            for (int k = 0; k < WIN; ++k) {
                uint4 u = v[o + k];
                h2 wk = w2[k];
                a0 += wk * uph(u.x);
                a1 += wk * uph(u.y);
                a2 += wk * uph(u.z);
                a3 += wk * uph(u.w);
            }
            #pragma unroll
            for (int h = 0; h < 2; ++h) {
                float mux = (float)a0[h];
                float muy = (float)a1[h];
                float es  = (float)a2[h];            /* E[x^2 + y^2] */
                float exy = (float)a3[h];
                float mux2 = mux * mux, muy2 = muy * muy, muxy = mux * muy;
                float num = (2.f * muxy + C1) * (2.f * (exy - muxy) + C2);
                float den = (mux2 + muy2 + C1) * ((es - mux2 - muy2) + C2);
                local += num * __builtin_amdgcn_rcpf(den + 1e-8f);
            }
        }
    }

    #pragma unroll
    for (int off = 32; off > 0; off >>= 1)
        local += __shfl_down(local, off, 64);
    if ((tid & 63) == 0) wsum[tid >> 6] = local;
    __syncthreads();
    if (tid == 0) {
        float bs = wsum[0] + wsum[1] + wsum[2] + wsum[3];
        if (USE_ATOMIC) {
            atomicAdd(outp, bs);
        } else {
            int bid = (blockIdx.z * NTILE + blockIdx.y) * NTILE + blockIdx.x;
            outp[bid] = bs;
        }
    }
}

// ---------------- Final reduce: 3072 partials -> out[0], one block ----------
__global__ void __launch_bounds__(256) reduce_kernel(
        const float* __restrict__ partial, float* __restrict__ out) {
    __shared__ float wsum[4];
    const int tid = threadIdx.x;
    float s = 0.f;
    for (int i = tid; i < NBLK; i += 256) s += partial[i];
    #pragma unroll
    for (int off = 32; off > 0; off >>= 1)
        s += __shfl_down(s, off, 64);
    if ((tid & 63) == 0) wsum[tid >> 6] = s;
    __syncthreads();
    if (tid == 0)
        out[0] = 1.0f - (wsum[0] + wsum[1] + wsum[2] + wsum[3]) * (float)(1.0 / NPIX);
}

extern "C" void kernel_launch(void* const* d_in, const int* in_sizes, int n_in,
                              void* d_out, int out_size, void* d_ws, size_t ws_size,
                              hipStream_t stream) {
    const float* x = (const float*)d_in[0];
    const float* y = (const float*)d_in[1];
    float* out = (float*)d_out;

    GaussW gw;
    double g[WIN], s = 0.0;
    for (int i = 0; i < WIN; ++i) {
        double d = (double)(i - WIN / 2);
        g[i] = exp(-(d * d) / (2.0 * 1.5 * 1.5));
        s += g[i];
    }
    for (int i = 0; i < WIN; ++i) gw.w[i] = (float)(g[i] / s);

    if (ws_size >= (size_t)NBLK * sizeof(float)) {
        float* partial = (float*)d_ws;
        hipLaunchKernelGGL((fused_ssim<0>), dim3(NTILE, NTILE, NIMG), dim3(256),
                           0, stream, x, y, partial, gw);
        hipLaunchKernelGGL(reduce_kernel, dim3(1), dim3(256), 0, stream,
                           partial, out);
    } else {
        hipLaunchKernelGGL(zero_kernel, dim3(1), dim3(64), 0, stream, out);
        hipLaunchKernelGGL((fused_ssim<1>), dim3(NTILE, NTILE, NIMG), dim3(256),
                           0, stream, x, y, out, gw);
        hipLaunchKernelGGL(finish_kernel, dim3(1), dim3(64), 0, stream, out);
    }
}

// Round 2
// 165.851 us; speedup vs baseline: 1.0489x; 1.0489x over previous
//
#include <hip/hip_runtime.h>
#include <cmath>

#define WIN 11
#define HALO 5
#define IMG 512
#define NIMG 48
#define TS 64                         /* output tile: 64x64 */
#define HR (TS + 2*HALO)              /* 74 h-blurred rows held in LDS */
#define NTILE (IMG/TS)                /* 8 tiles per axis */
#define NBLK (NIMG*NTILE*NTILE)       /* 3072 blocks / partials */
#define NPIX (16.0 * 3.0 * 512.0 * 512.0)

typedef _Float16 f16;
typedef _Float16 h2 __attribute__((ext_vector_type(2)));

struct GaussW { float w[WIN]; };

__device__ __forceinline__ unsigned pk2(float a, float b) {
    auto h = __builtin_amdgcn_cvt_pkrtz(a, b);
    return __builtin_bit_cast(unsigned, h);
}
__device__ __forceinline__ h2 uph(unsigned u) {
    return __builtin_bit_cast(h2, u);
}

__global__ void __launch_bounds__(64) zero_kernel(float* out) {
    if (threadIdx.x == 0) out[0] = 0.f;
}

__global__ void __launch_bounds__(64) finish_kernel(float* out) {
    if (threadIdx.x == 0)
        out[0] = 1.0f - out[0] * (float)(1.0 / NPIX);
}

// ---------------- Fused h-blur + v-blur + SSIM, one 64x64 tile per block ----
// R1 post-mortem: 256-thr version ran 86.5us @ 27.7% occupancy, VGPR=52 --
// too small to hold the phase-2 uint4 v[14] window, so the compiler was
// re-reading LDS inside the tap loop (~3x DS bloat), and 16 waves/CU max
// couldn't hide phase-1 global latency.
// This version: 512 threads, __launch_bounds__(512,8) -> 4 blocks/CU
// (38.4KB LDS x4 = 153.6KB) = 32 waves/CU; phase 2 is STREAMED (one
// ds_read_b128 per input row, fixed acc[4][4] window, ~35 live VGPRs).
template<int USE_ATOMIC>
__global__ void __launch_bounds__(512, 8) fused_ssim(
        const float* __restrict__ xin, const float* __restrict__ yin,
        float* __restrict__ outp, GaussW W) {
    __shared__ uint4 hb[HR][32];      /* 74 * 512B = 37,888 B */
    __shared__ float wsum[8];
    const int tid = threadIdx.x;
    const int tx = blockIdx.x, ty = blockIdx.y;
    const size_t ibase = (size_t)blockIdx.z * (size_t)(IMG * IMG);
    const float* __restrict__ xb = xin + ibase;
    const float* __restrict__ yb = yin + ibase;

    // ---- phase 1: horizontal blur of image rows ty*64-5 .. ty*64+68 ----
    // 512 thr = 16 colgroups x 32 rows; 3 passes cover the 74 halo'd rows.
    const int cg  = tid & 15;                 /* 4 output cols per thread */
    const int rr  = tid >> 4;                 /* 0..31 */
    const int gx0 = tx * TS + cg * 4 - HALO;  /* 14-col window gx0..gx0+13 */
    const bool cint = (gx0 >= 0) && (gx0 + 13 < IMG);

    #pragma unroll
    for (int it = 0; it < 3; ++it) {
        const int r = it * 32 + rr;           /* 0..95, keep r < 74 */
        if (r < HR) {
            const int gy = ty * TS - HALO + r;
            if ((unsigned)gy < IMG) {
                const float* xr = xb + (size_t)gy * IMG;
                const float* yr = yb + (size_t)gy * IMG;
                float xv[14], yv[14];
                if (cint) {
                    xv[0] = xr[gx0];  yv[0] = yr[gx0];
                    #pragma unroll
                    for (int q = 0; q < 3; ++q) {     /* 16B-aligned float4s */
                        float4 a = *(const float4*)(xr + gx0 + 1 + 4*q);
                        float4 b = *(const float4*)(yr + gx0 + 1 + 4*q);
                        xv[1+4*q]=a.x; xv[2+4*q]=a.y; xv[3+4*q]=a.z; xv[4+4*q]=a.w;
                        yv[1+4*q]=b.x; yv[2+4*q]=b.y; yv[3+4*q]=b.z; yv[4+4*q]=b.w;
                    }
                    xv[13] = xr[gx0 + 13];  yv[13] = yr[gx0 + 13];
                } else {
                    #pragma unroll
                    for (int j = 0; j < 14; ++j) {
                        int gx = gx0 + j;
                        bool ok = ((unsigned)gx < IMG);
                        xv[j] = ok ? xr[gx] : 0.f;
                        yv[j] = ok ? yr[gx] : 0.f;
                    }
                }
                float ax[4]  = {0,0,0,0}, ay[4]  = {0,0,0,0};
                float as_[4] = {0,0,0,0}, axy[4] = {0,0,0,0};
                #pragma unroll
                for (int j = 0; j < 14; ++j) {
                    float xs = xv[j], ys = yv[j];
                    float xy = xs * ys;
                    float ss = fmaf(xs, xs, ys * ys);   /* x^2+y^2 one field */
                    #pragma unroll
                    for (int o = 0; o < 4; ++o) {
                        int k = j - o;
                        if (k >= 0 && k < WIN) {
                            float wk = W.w[k];
                            ax[o]  += wk * xs;  ay[o]  += wk * ys;
                            as_[o] += wk * ss;  axy[o] += wk * xy;
                        }
                    }
                }
                uint4 u0, u1;
                u0.x = pk2(ax[0],  ax[1]);  u0.y = pk2(ay[0],  ay[1]);
                u0.z = pk2(as_[0], as_[1]); u0.w = pk2(axy[0], axy[1]);
                u1.x = pk2(ax[2],  ax[3]);  u1.y = pk2(ay[2],  ay[3]);
                u1.z = pk2(as_[2], as_[3]); u1.w = pk2(axy[2], axy[3]);
                hb[r][cg]      = u0;          /* even col-pair */
                hb[r][cg + 16] = u1;          /* odd col-pair  */
            } else {
                uint4 z = make_uint4(0u, 0u, 0u, 0u);
                hb[r][cg]      = z;
                hb[r][cg + 16] = z;
            }
        }
    }
    __syncthreads();

    // ---- phase 2: vertical blur (fp16 packed) + SSIM + block reduce ----
    // 512 thr = 32 col-pairs x 16 rowgroups of 4 output rows.  STREAMED:
    // one ds_read_b128 per input row j, accumulate into acc[o][field].
    const int idx = tid & 31;                 /* LDS col-pair slot */
    const int rbase = (tid >> 5) * 4;         /* first of 14 input rows */

    h2 w2[WIN];
    #pragma unroll
    for (int k = 0; k < WIN; ++k) {
        f16 wk = (f16)W.w[k];
        w2[k] = (h2){wk, wk};
    }

    h2 acc[4][4];
    #pragma unroll
    for (int o = 0; o < 4; ++o)
        #pragma unroll
        for (int f = 0; f < 4; ++f)
            acc[o][f] = (h2){(f16)0, (f16)0};

    #pragma unroll
    for (int j = 0; j < 14; ++j) {
        uint4 u = hb[rbase + j][idx];
        h2 f0 = uph(u.x), f1 = uph(u.y), f2 = uph(u.z), f3 = uph(u.w);
        #pragma unroll
        for (int o = 0; o < 4; ++o) {
            int k = j - o;
            if (k >= 0 && k < WIN) {
                h2 wk = w2[k];
                acc[o][0] += wk * f0;
                acc[o][1] += wk * f1;
                acc[o][2] += wk * f2;
                acc[o][3] += wk * f3;
            }
        }
    }

    const float C1 = 0.01f * 0.01f;
    const float C2 = 0.03f * 0.03f;
    float local = 0.f;
    #pragma unroll
    for (int o = 0; o < 4; ++o) {
        #pragma unroll
        for (int h = 0; h < 2; ++h) {
            float mux = (float)acc[o][0][h];
            float muy = (float)acc[o][1][h];
            float es  = (float)acc[o][2][h];         /* E[x^2 + y^2] */
            float exy = (float)acc[o][3][h];
            float mux2 = mux * mux, muy2 = muy * muy, muxy = mux * muy;
            float num = (2.f * muxy + C1) * (2.f * (exy - muxy) + C2);
            float den = (mux2 + muy2 + C1) * ((es - mux2 - muy2) + C2);
            local += num * __builtin_amdgcn_rcpf(den + 1e-8f);
        }
    }

    #pragma unroll
    for (int off = 32; off > 0; off >>= 1)
        local += __shfl_down(local, off, 64);
    if ((tid & 63) == 0) wsum[tid >> 6] = local;
    __syncthreads();
    if (tid == 0) {
        float bs = 0.f;
        #pragma unroll
        for (int wv = 0; wv < 8; ++wv) bs += wsum[wv];
        if (USE_ATOMIC) {
            atomicAdd(outp, bs);
        } else {
            int bid = (blockIdx.z * NTILE + blockIdx.y) * NTILE + blockIdx.x;
            outp[bid] = bs;
        }
    }
}

// ---------------- Final reduce: 3072 partials -> out[0], one block ----------
__global__ void __launch_bounds__(256) reduce_kernel(
        const float* __restrict__ partial, float* __restrict__ out) {
    __shared__ float wsum[4];
    const int tid = threadIdx.x;
    float s = 0.f;
    for (int i = tid; i < NBLK; i += 256) s += partial[i];
    #pragma unroll
    for (int off = 32; off > 0; off >>= 1)
        s += __shfl_down(s, off, 64);
    if ((tid & 63) == 0) wsum[tid >> 6] = s;
    __syncthreads();
    if (tid == 0)
        out[0] = 1.0f - (wsum[0] + wsum[1] + wsum[2] + wsum[3]) * (float)(1.0 / NPIX);
}

extern "C" void kernel_launch(void* const* d_in, const int* in_sizes, int n_in,
                              void* d_out, int out_size, void* d_ws, size_t ws_size,
                              hipStream_t stream) {
    const float* x = (const float*)d_in[0];
    const float* y = (const float*)d_in[1];
    float* out = (float*)d_out;

    GaussW gw;
    double g[WIN], s = 0.0;
    for (int i = 0; i < WIN; ++i) {
        double d = (double)(i - WIN / 2);
        g[i] = exp(-(d * d) / (2.0 * 1.5 * 1.5));
        s += g[i];
    }
    for (int i = 0; i < WIN; ++i) gw.w[i] = (float)(g[i] / s);

    if (ws_size >= (size_t)NBLK * sizeof(float)) {
        float* partial = (float*)d_ws;
        hipLaunchKernelGGL((fused_ssim<0>), dim3(NTILE, NTILE, NIMG), dim3(512),
                           0, stream, x, y, partial, gw);
        hipLaunchKernelGGL(reduce_kernel, dim3(1), dim3(256), 0, stream,
                           partial, out);
    } else {
        hipLaunchKernelGGL(zero_kernel, dim3(1), dim3(64), 0, stream, out);
        hipLaunchKernelGGL((fused_ssim<1>), dim3(NTILE, NTILE, NIMG), dim3(512),
                           0, stream, x, y, out, gw);
        hipLaunchKernelGGL(finish_kernel, dim3(1), dim3(64), 0, stream, out);
    }
}

// Round 5
// 164.876 us; speedup vs baseline: 1.0551x; 1.0059x over previous
//
#include <hip/hip_runtime.h>
#include <cmath>

#define WIN 11
#define HALO 5
#define IMG 512
#define NIMG 48
#define TS 64                         /* output tile: 64x64 */
#define HR (TS + 2*HALO)              /* 74 h-blurred rows held in LDS */
#define NTILE (IMG/TS)                /* 8 tiles per axis */
#define NBLK (NIMG*NTILE*NTILE)       /* 3072 blocks / partials */
#define NPIX (16.0 * 3.0 * 512.0 * 512.0)

typedef _Float16 f16;
typedef _Float16 h2 __attribute__((ext_vector_type(2)));

/* packed fp16 {w,w} weights, built on host -> kernarg -> SGPR operands */
struct GaussW { unsigned hw[WIN]; };

__device__ __forceinline__ unsigned pk2(float a, float b) {
    auto h = __builtin_amdgcn_cvt_pkrtz(a, b);
    return __builtin_bit_cast(unsigned, h);
}
__device__ __forceinline__ h2 uph(unsigned u) {
    return __builtin_bit_cast(h2, u);
}
__device__ __forceinline__ unsigned dnh(h2 v) {
    return __builtin_bit_cast(unsigned, v);
}

__global__ void __launch_bounds__(64) zero_kernel(float* out) {
    if (threadIdx.x == 0) out[0] = 0.f;
}

__global__ void __launch_bounds__(64) finish_kernel(float* out) {
    if (threadIdx.x == 0)
        out[0] = 1.0f - out[0] * (float)(1.0 / NPIX);
}

// ---------------- Fused h-blur + v-blur + SSIM, one 64x64 tile per block ----
// R2 post-mortem: 78.7us, VALUBusy 60%, same dur with L3-resident inputs ->
// pure VALU/latency kernel.  Phase 1's fp32 h-blur (176 v_fma_f32 per
// thread-row) was ~2/3 of the instruction count.
// This version packs the h-blur: {x,y} and {x^2+y^2, x*y} as h2 pairs ->
// 88 v_pk_fma_f16, no output pack.  Weights are packed fp16 in the kernarg
// (SGPR operands, zero setup).  Phase 2 tap loop unchanged; epilogue now
// extracts {mux,muy} / {es,exy} from paired accumulators.
template<int USE_ATOMIC>
__global__ void __launch_bounds__(512, 8) fused_ssim(
        const float* __restrict__ xin, const float* __restrict__ yin,
        float* __restrict__ outp, GaussW W) {
    __shared__ uint4 hb[HR][32];      /* 74 * 512B = 37,888 B */
    __shared__ float wsum[8];
    const int tid = threadIdx.x;
    const int tx = blockIdx.x, ty = blockIdx.y;
    const size_t ibase = (size_t)blockIdx.z * (size_t)(IMG * IMG);
    const float* __restrict__ xb = xin + ibase;
    const float* __restrict__ yb = yin + ibase;

    // ---- phase 1: horizontal blur of image rows ty*64-5 .. ty*64+68 ----
    // 512 thr = 16 colgroups x 32 rows; 3 passes cover the 74 halo'd rows.
    const int cg  = tid & 15;                 /* 4 output cols per thread */
    const int rr  = tid >> 4;                 /* 0..31 */
    const int gx0 = tx * TS + cg * 4 - HALO;  /* 14-col window gx0..gx0+13 */
    const bool cint = (gx0 >= 0) && (gx0 + 13 < IMG);

    #pragma unroll
    for (int it = 0; it < 3; ++it) {
        const int r = it * 32 + rr;           /* 0..95, keep r < 74 */
        if (r < HR) {
            const int gy = ty * TS - HALO + r;
            if ((unsigned)gy < IMG) {
                const float* xr = xb + (size_t)gy * IMG;
                const float* yr = yb + (size_t)gy * IMG;
                float xv[14], yv[14];
                if (cint) {
                    xv[0] = xr[gx0];  yv[0] = yr[gx0];
                    #pragma unroll
                    for (int q = 0; q < 3; ++q) {     /* 16B-aligned float4s */
                        float4 a = *(const float4*)(xr + gx0 + 1 + 4*q);
                        float4 b = *(const float4*)(yr + gx0 + 1 + 4*q);
                        xv[1+4*q]=a.x; xv[2+4*q]=a.y; xv[3+4*q]=a.z; xv[4+4*q]=a.w;
                        yv[1+4*q]=b.x; yv[2+4*q]=b.y; yv[3+4*q]=b.z; yv[4+4*q]=b.w;
                    }
                    xv[13] = xr[gx0 + 13];  yv[13] = yr[gx0 + 13];
                } else {
                    #pragma unroll
                    for (int j = 0; j < 14; ++j) {
                        int gx = gx0 + j;
                        bool ok = ((unsigned)gx < IMG);
                        xv[j] = ok ? xr[gx] : 0.f;
                        yv[j] = ok ? yr[gx] : 0.f;
                    }
                }
                /* packed h-blur: a0 = blur{x,y}, a1 = blur{x^2+y^2, x*y} */
                h2 a0[4], a1[4];
                #pragma unroll
                for (int o = 0; o < 4; ++o) {
                    a0[o] = (h2){(f16)0, (f16)0};
                    a1[o] = (h2){(f16)0, (f16)0};
                }
                #pragma unroll
                for (int j = 0; j < 14; ++j) {
                    float xs = xv[j], ys = yv[j];
                    float xy = xs * ys;
                    float ss = fmaf(xs, xs, ys * ys);
                    h2 c0 = uph(pk2(xs, ys));
                    h2 c1 = uph(pk2(ss, xy));
                    #pragma unroll
                    for (int o = 0; o < 4; ++o) {
                        int k = j - o;
                        if (k >= 0 && k < WIN) {
                            h2 wk = uph(W.hw[k]);     /* SGPR operand */
                            a0[o] += wk * c0;
                            a1[o] += wk * c1;
                        }
                    }
                }
                /* uint4 = {col even: c0,c1, col odd: c0,c1} */
                uint4 u0, u1;
                u0.x = dnh(a0[0]); u0.y = dnh(a1[0]);
                u0.z = dnh(a0[1]); u0.w = dnh(a1[1]);
                u1.x = dnh(a0[2]); u1.y = dnh(a1[2]);
                u1.z = dnh(a0[3]); u1.w = dnh(a1[3]);
                hb[r][cg]      = u0;          /* cols 4cg,4cg+1 */
                hb[r][cg + 16] = u1;          /* cols 4cg+2,4cg+3 */
            } else {
                uint4 z = make_uint4(0u, 0u, 0u, 0u);
                hb[r][cg]      = z;
                hb[r][cg + 16] = z;
            }
        }
    }
    __syncthreads();

    // ---- phase 2: vertical blur (fp16 packed) + SSIM + block reduce ----
    // 512 thr = 32 col-slots x 16 rowgroups of 4 output rows.  STREAMED:
    // one ds_read_b128 per input row j, accumulate into acc[o][field].
    const int idx = tid & 31;                 /* LDS col-slot (2 cols) */
    const int rbase = (tid >> 5) * 4;         /* first of 14 input rows */

    h2 acc[4][4];
    #pragma unroll
    for (int o = 0; o < 4; ++o)
        #pragma unroll
        for (int f = 0; f < 4; ++f)
            acc[o][f] = (h2){(f16)0, (f16)0};

    #pragma unroll
    for (int j = 0; j < 14; ++j) {
        uint4 u = hb[rbase + j][idx];
        h2 f0 = uph(u.x), f1 = uph(u.y), f2 = uph(u.z), f3 = uph(u.w);
        #pragma unroll
        for (int o = 0; o < 4; ++o) {
            int k = j - o;
            if (k >= 0 && k < WIN) {
                h2 wk = uph(W.hw[k]);         /* SGPR operand */
                acc[o][0] += wk * f0;
                acc[o][1] += wk * f1;
                acc[o][2] += wk * f2;
                acc[o][3] += wk * f3;
            }
        }
    }

    const float C1 = 0.01f * 0.01f;
    const float C2 = 0.03f * 0.03f;
    float local = 0.f;
    #pragma unroll
    for (int o = 0; o < 4; ++o) {
        #pragma unroll
        for (int p = 0; p < 2; ++p) {         /* even col (p=0), odd (p=1) */
            h2 m  = acc[o][2*p];              /* {mu_x, mu_y}   */
            h2 se = acc[o][2*p+1];            /* {E[ss], E[xy]} */
            float mux = (float)m[0];
            float muy = (float)m[1];
            float es  = (float)se[0];
            float exy = (float)se[1];
            float mux2 = mux * mux, muy2 = muy * muy, muxy = mux * muy;
            float num = (2.f * muxy + C1) * (2.f * (exy - muxy) + C2);
            float den = (mux2 + muy2 + C1) * ((es - mux2 - muy2) + C2);
            local += num * __builtin_amdgcn_rcpf(den + 1e-8f);
        }
    }

    #pragma unroll
    for (int off = 32; off > 0; off >>= 1)
        local += __shfl_down(local, off, 64);
    if ((tid & 63) == 0) wsum[tid >> 6] = local;
    __syncthreads();
    if (tid == 0) {
        float bs = 0.f;
        #pragma unroll
        for (int wv = 0; wv < 8; ++wv) bs += wsum[wv];
        if (USE_ATOMIC) {
            atomicAdd(outp, bs);
        } else {
            int bid = (blockIdx.z * NTILE + blockIdx.y) * NTILE + blockIdx.x;
            outp[bid] = bs;
        }
    }
}

// ---------------- Final reduce: 3072 partials -> out[0], one block ----------
__global__ void __launch_bounds__(256) reduce_kernel(
        const float* __restrict__ partial, float* __restrict__ out) {
    __shared__ float wsum[4];
    const int tid = threadIdx.x;
    float s = 0.f;
    for (int i = tid; i < NBLK; i += 256) s += partial[i];
    #pragma unroll
    for (int off = 32; off > 0; off >>= 1)
        s += __shfl_down(s, off, 64);
    if ((tid & 63) == 0) wsum[tid >> 6] = s;
    __syncthreads();
    if (tid == 0)
        out[0] = 1.0f - (wsum[0] + wsum[1] + wsum[2] + wsum[3]) * (float)(1.0 / NPIX);
}

extern "C" void kernel_launch(void* const* d_in, const int* in_sizes, int n_in,
                              void* d_out, int out_size, void* d_ws, size_t ws_size,
                              hipStream_t stream) {
    const float* x = (const float*)d_in[0];
    const float* y = (const float*)d_in[1];
    float* out = (float*)d_out;

    /* fp32 Gaussian weights */
    double g[WIN], s = 0.0;
    for (int i = 0; i < WIN; ++i) {
        double d = (double)(i - WIN / 2);
        g[i] = exp(-(d * d) / (2.0 * 1.5 * 1.5));
        s += g[i];
    }
    float wf[WIN];
    for (int i = 0; i < WIN; ++i) wf[i] = (float)(g[i] / s);

    /* pack to fp16 {w,w}; renormalize center tap so fp16 weight sum == 1 */
    GaussW gw;
    _Float16 wh[WIN];
    double hsum = 0.0;
    for (int i = 0; i < WIN; ++i) { wh[i] = (_Float16)wf[i]; hsum += (double)(float)wh[i]; }
    wh[WIN/2] = (_Float16)((float)wh[WIN/2] + (float)(1.0 - hsum));
    for (int i = 0; i < WIN; ++i) {
        unsigned short b = __builtin_bit_cast(unsigned short, wh[i]);
        gw.hw[i] = (unsigned)b | ((unsigned)b << 16);
    }

    if (ws_size >= (size_t)NBLK * sizeof(float)) {
        float* partial = (float*)d_ws;
        hipLaunchKernelGGL((fused_ssim<0>), dim3(NTILE, NTILE, NIMG), dim3(512),
                           0, stream, x, y, partial, gw);
        hipLaunchKernelGGL(reduce_kernel, dim3(1), dim3(256), 0, stream,
                           partial, out);
    } else {
        hipLaunchKernelGGL(zero_kernel, dim3(1), dim3(64), 0, stream, out);
        hipLaunchKernelGGL((fused_ssim<1>), dim3(NTILE, NTILE, NIMG), dim3(512),
                           0, stream, x, y, out, gw);
        hipLaunchKernelGGL(finish_kernel, dim3(1), dim3(64), 0, stream, out);
    }
}